// Round 3
// baseline (387.795 us; speedup 1.0000x reference)
//
#include <hip/hip_runtime.h>
#include <math.h>

#define HALO 10
#define TS 32
#define IN 42      // TS + HALO rows staged
#define NP 21      // float2 pairs staged per row (42 cols; window needs <=41)
#define XSTR 46    // LDS row stride (words) for Xs/Ys
#define HSTR 46    // LDS row stride (words) for Hs (transposed)
#define NBIN 256   // atomic spreading: one 64B line (16 floats) per bin per level
#define NG 64      // barrier groups (each counter/gen copy on its own 64B line)
#define BARW 2112  // uints reserved for barrier state (16 + 64*16 + 64*16 = 2064, padded)

typedef float f2 __attribute__((ext_vector_type(2)));

struct GaussW { float g[11]; };

// ---------------- device-scope grid barrier (capture-safe, no cooperative API) ----
// bar layout (uints): [0] root counter | [16 + g*16] group counters | [16+NG*16 + g*16] gen copies
// Requires gridDim.x % NG == 0 and all blocks co-resident (guaranteed by
// __launch_bounds__(256,6): 23.6KB LDS*6=141KB<=160KB, VGPR<=85 -> 6 blocks/CU).
__device__ __forceinline__ void grid_barrier(unsigned* bar)
{
    __syncthreads();
    if (threadIdx.x == 0) {
        unsigned* root  = bar;
        unsigned* grp   = bar + 16 + (blockIdx.x & (NG - 1)) * 16;
        unsigned* mygen = bar + 16 + NG * 16 + (blockIdx.x & (NG - 1)) * 16;
        const unsigned gsz = gridDim.x / NG;

        // read my epoch BEFORE arriving (release side of fetch_add keeps order)
        unsigned gen = __hip_atomic_load(mygen, __ATOMIC_RELAXED, __HIP_MEMORY_SCOPE_AGENT);
        unsigned a = __hip_atomic_fetch_add(grp, 1u, __ATOMIC_ACQ_REL, __HIP_MEMORY_SCOPE_AGENT);
        if (a == gsz - 1) {                       // last of my group
            __hip_atomic_store(grp, 0u, __ATOMIC_RELAXED, __HIP_MEMORY_SCOPE_AGENT);
            unsigned r = __hip_atomic_fetch_add(root, 1u, __ATOMIC_ACQ_REL, __HIP_MEMORY_SCOPE_AGENT);
            if (r == NG - 1) {                    // last overall: release everyone
                __hip_atomic_store(root, 0u, __ATOMIC_RELAXED, __HIP_MEMORY_SCOPE_AGENT);
                unsigned* gc = bar + 16 + NG * 16;
                #pragma unroll 4
                for (int i = 0; i < NG; ++i)
                    __hip_atomic_store(gc + i * 16, gen + 1, __ATOMIC_RELEASE, __HIP_MEMORY_SCOPE_AGENT);
            }
        }
        unsigned spin = 0;
        while (__hip_atomic_load(mygen, __ATOMIC_RELAXED, __HIP_MEMORY_SCOPE_AGENT) == gen) {
            __builtin_amdgcn_s_sleep(4);
            if (++spin > (1u << 20)) break;       // watchdog: wrong > hung
        }
        __builtin_amdgcn_fence(__ATOMIC_ACQUIRE, "agent");
    }
    __syncthreads();
}

// ---------------- per-tile SSIM level body (identical math to the 201us kernel) ----
// LDS union U (4*TS*HSTR words = 23552 B):
//   phase 1-2a: Xs[IN][XSTR] @ U, Ys[IN][XSTR] @ U+IN*XSTR
//   phase 2b-3: Hs[4][TS][HSTR] aliases the whole region (all Xs/Ys reads
//   complete before the barrier preceding the first Hs write).
__device__ __forceinline__ void ssim_tile(
    const float* __restrict__ X, const float* __restrict__ Y,
    int H, const GaussW& gw, float* __restrict__ Plevel, int last_level,
    float* __restrict__ Xpool, float* __restrict__ Ypool,
    int bc, int r0, int c0, int lin, float* U, float* red)
{
    const int W = H;
    const int Hout = H - HALO;
    float* Xs = U;                    // [IN][XSTR]
    float* Ys = U + IN * XSTR;        // [IN][XSTR]
    const int tid = threadIdx.x;
    const int b   = bc / 3;
    const size_t base = (size_t)bc * H * W;

    // Phase 1: coalesced staging
    for (int idx = tid; idx < IN * NP; idx += 256) {
        int rr = idx / NP, pp = idx - rr * NP;
        int gr = r0 + rr, gc = c0 + 2 * pp;
        float2 xv = make_float2(0.f, 0.f), yv = make_float2(0.f, 0.f);
        if (gr < H && gc < W) {
            const float* xp = X + base + (size_t)gr * W + gc;
            const float* yp = Y + base + (size_t)gr * W + gc;
            xv = *(const float2*)xp;
            yv = *(const float2*)yp;
        }
        *(float2*)&Xs[rr * XSTR + 2 * pp] = xv;
        *(float2*)&Ys[rr * XSTR + 2 * pp] = yv;
    }
    __syncthreads();

    // Phase 2a: windows -> registers (waves 0-2); 2x2 pool (wave 3)
    float x[18], y[18];
    int rr = 0, ccb = 0;
    if (tid < 168) {
        rr  = tid >> 2;
        ccb = (tid & 3) * 8;
        #pragma unroll
        for (int u = 0; u < 9; ++u) {
            *(f2*)&x[2 * u] = *(const f2*)&Xs[rr * XSTR + ccb + 2 * u];
            *(f2*)&y[2 * u] = *(const f2*)&Ys[rr * XSTR + ccb + 2 * u];
        }
    } else if (tid >= 192 && !last_level) {
        const int t = tid - 192;
        const int Wp = W >> 1;
        #pragma unroll
        for (int q = 0; q < 4; ++q) {
            int cell = q * 64 + t;
            int pr = cell >> 4, pc = cell & 15;
            float2 xa = *(const float2*)&Xs[(2 * pr)     * XSTR + 2 * pc];
            float2 xb = *(const float2*)&Xs[(2 * pr + 1) * XSTR + 2 * pc];
            float2 ya = *(const float2*)&Ys[(2 * pr)     * XSTR + 2 * pc];
            float2 yb = *(const float2*)&Ys[(2 * pr + 1) * XSTR + 2 * pc];
            size_t o = (size_t)bc * (H >> 1) * Wp + (size_t)(r0 / 2 + pr) * Wp + (c0 / 2 + pc);
            Xpool[o] = 0.25f * (xa.x + xa.y + xb.x + xb.y);
            Ypool[o] = 0.25f * (ya.x + ya.y + yb.x + yb.y);
        }
    }
    __syncthreads();   // all Xs/Ys reads done -> Hs may overwrite

    // Phase 2b: horizontal 11-tap blur of {x, y, (x+y)^2, (x-y)^2}
    if (tid < 168) {
        #pragma unroll
        for (int p = 0; p < 4; ++p) {
            f2 ax = {0.f, 0.f}, ay = {0.f, 0.f};
            #pragma unroll
            for (int k = 0; k < 11; ++k) {
                f2 vx = { x[2 * p + k], x[2 * p + k + 1] };
                f2 vy = { y[2 * p + k], y[2 * p + k + 1] };
                ax += vx * gw.g[k];
                ay += vy * gw.g[k];
            }
            U[(0 * TS + ccb + 2 * p    ) * HSTR + rr] = ax.x;
            U[(0 * TS + ccb + 2 * p + 1) * HSTR + rr] = ax.y;
            U[(1 * TS + ccb + 2 * p    ) * HSTR + rr] = ay.x;
            U[(1 * TS + ccb + 2 * p + 1) * HSTR + rr] = ay.y;
        }
        #pragma unroll
        for (int i = 0; i < 9; ++i) {
            f2 xv = *(f2*)&x[2 * i];
            f2 yv = *(f2*)&y[2 * i];
            f2 a = xv + yv;
            f2 d = xv - yv;
            *(f2*)&x[2 * i] = a * a;
            *(f2*)&y[2 * i] = d * d;
        }
        #pragma unroll
        for (int p = 0; p < 4; ++p) {
            f2 as = {0.f, 0.f}, ad = {0.f, 0.f};
            #pragma unroll
            for (int k = 0; k < 11; ++k) {
                f2 vs = { x[2 * p + k], x[2 * p + k + 1] };
                f2 vd = { y[2 * p + k], y[2 * p + k + 1] };
                as += vs * gw.g[k];
                ad += vd * gw.g[k];
            }
            U[(2 * TS + ccb + 2 * p    ) * HSTR + rr] = as.x;
            U[(2 * TS + ccb + 2 * p + 1) * HSTR + rr] = as.y;
            U[(3 * TS + ccb + 2 * p    ) * HSTR + rr] = ad.x;
            U[(3 * TS + ccb + 2 * p + 1) * HSTR + rr] = ad.y;
        }
    }
    __syncthreads();

    // Phase 3: vertical 11-tap blur + SSIM
    const int tx = tid & 31;
    const int ty = tid >> 5;
    const int rb = ty * 4;

    f2 m1[2], m2[2], S[2], D[2];
    #define VPASS(Q, OUT)                                                          \
    {                                                                              \
        float win[14];                                                             \
        _Pragma("unroll")                                                          \
        for (int i = 0; i < 7; ++i)                                                \
            *(f2*)&win[2 * i] = *(const f2*)&U[(Q * TS + tx) * HSTR + rb + 2 * i]; \
        _Pragma("unroll")                                                          \
        for (int h = 0; h < 2; ++h) {                                              \
            f2 acc = {0.f, 0.f};                                                   \
            _Pragma("unroll")                                                      \
            for (int k = 0; k < 11; ++k) {                                         \
                f2 v = { win[2 * h + k], win[2 * h + k + 1] };                     \
                acc += v * gw.g[k];                                                \
            }                                                                      \
            OUT[h] = acc;                                                          \
        }                                                                          \
    }
    VPASS(0, m1) VPASS(1, m2) VPASS(2, S) VPASS(3, D)
    #undef VPASS

    const float C1 = 1e-4f, C2 = 9e-4f;
    float acc_s = 0.f;
    #pragma unroll
    for (int o = 0; o < 4; ++o) {
        float u1 = m1[o >> 1][o & 1], u2 = m2[o >> 1][o & 1];
        float Sv = S[o >> 1][o & 1],  Dv = D[o >> 1][o & 1];
        float u1s = u1 * u1, u2s = u2 * u2, u12 = u1 * u2;
        float ssum = 0.5f  * (Sv + Dv);
        float sxy  = 0.25f * (Sv - Dv);
        float vsum = ssum - u1s - u2s;
        float v12  = sxy - u12;
        float A2   = fmaxf(2.f * v12 + C2, 0.f);
        float B1   = u1s + u2s + C1;
        float B2   = vsum + C2;
        float inv  = __builtin_amdgcn_rcpf(B1 * B2);
        float val;
        if (!last_level) {
            val = A2 * B1 * inv;
        } else {
            float A1 = 2.f * u12 + C1;
            val = A1 * A2 * inv;
        }
        bool valid = (r0 + rb + o < Hout) && (c0 + tx < Hout);
        acc_s += valid ? val : 0.f;
    }

    // Phase 4: block reduction + one atomic
    #pragma unroll
    for (int off = 32; off; off >>= 1) acc_s += __shfl_down(acc_s, off);
    if ((tid & 63) == 0) red[tid >> 6] = acc_s;
    __syncthreads();
    if (tid == 0) {
        int bin = lin & (NBIN - 1);
        atomicAdd(&Plevel[bin * 16 + b], red[0] + red[1] + red[2] + red[3]);
    }
}

// ---------------- fused persistent kernel: all 4 levels + finalize ----------------
__global__ __launch_bounds__(256, 6) void ms_ssim_mega(
    const float* __restrict__ X0, const float* __restrict__ Y0,
    float* __restrict__ ws, float* __restrict__ out, GaussW gw)
{
    __shared__ float U[4 * TS * HSTR];
    __shared__ float red[4];

    unsigned* bar = (unsigned*)ws;
    const size_t PSZ = (size_t)4 * NBIN * 16;
    float* P  = ws + BARW;
    float* X1 = P  + PSZ;
    float* Y1 = X1 + (size_t)16 * 3 * 256 * 256;
    float* X2 = Y1 + (size_t)16 * 3 * 256 * 256;
    float* Y2 = X2 + (size_t)16 * 3 * 128 * 128;
    float* X3 = Y2 + (size_t)16 * 3 * 128 * 128;
    float* Y3 = X3 + (size_t)16 * 3 * 64 * 64;

    #pragma unroll 1
    for (int L = 0; L < 4; ++L) {
        const int H   = 512 >> L;
        const int lg2 = 2 * (4 - L);          // log2((H/32)^2): 8,6,4,2
        const int ntiles = 48 << lg2;
        const int last = (L == 3);
        float* Pl = P + L * NBIN * 16;
        const float *Xi, *Yi; float *Xo, *Yo;
        if      (L == 0) { Xi = X0; Yi = Y0; Xo = X1; Yo = Y1; }
        else if (L == 1) { Xi = X1; Yi = Y1; Xo = X2; Yo = Y2; }
        else if (L == 2) { Xi = X2; Yi = Y2; Xo = X3; Yo = Y3; }
        else             { Xi = X3; Yi = Y3; Xo = nullptr; Yo = nullptr; }

        for (int t = blockIdx.x; t < ntiles; t += gridDim.x) {
            const int bc  = t >> lg2;
            const int rem = t & ((1 << lg2) - 1);
            const int tyi = rem >> (4 - L);
            const int txi = rem & ((H >> 5) - 1);
            ssim_tile(Xi, Yi, H, gw, Pl, last, Xo, Yo,
                      bc, tyi * TS, txi * TS, t, U, red);
        }
        grid_barrier(bar);
    }

    // finalize in block 0 (reuse U as scratch)
    if (blockIdx.x == 0) {
        float* fin = U;                    // [64][4]
        const int tid  = threadIdx.x;
        const int pair = tid >> 2;
        const int chnk = tid & 3;
        const int l = pair >> 4, b = pair & 15;
        float s = 0.f;
        #pragma unroll 4
        for (int j = 0; j < 64; ++j)
            s += P[((l * NBIN) + (chnk * 64) + j) * 16 + b];
        fin[pair * 4 + chnk] = s;
        __syncthreads();
        if (tid < 16) {
            const int bb = tid;
            const float wraw[4] = {0.0448f, 0.2856f, 0.3001f, 0.2363f};
            float wsum = wraw[0] + wraw[1] + wraw[2] + wraw[3];
            float ms = 1.f;
            for (int ll = 0; ll < 4; ++ll) {
                int Hh = 512 >> ll;
                int Ho = Hh - HALO;
                float cnt = 3.f * (float)Ho * (float)Ho;
                float val = (fin[(ll * 16 + bb) * 4 + 0] + fin[(ll * 16 + bb) * 4 + 1] +
                             fin[(ll * 16 + bb) * 4 + 2] + fin[(ll * 16 + bb) * 4 + 3]) / cnt;
                val = fmaxf(val, 1e-8f);
                ms *= powf(val, wraw[ll] / wsum);
            }
            out[bb] = 1.f - ms;
        }
    }
}

// ---------------- fallback: proven per-level chain (201us) ----------------
__global__ __launch_bounds__(256, 6) void ssim_level_kernel(
    const float* __restrict__ X, const float* __restrict__ Y,
    int H, GaussW gw, float* __restrict__ Plevel, int last_level,
    float* __restrict__ Xpool, float* __restrict__ Ypool)
{
    __shared__ float U[4 * TS * HSTR];
    __shared__ float red[4];
    const int bc = blockIdx.z;
    const int lin = blockIdx.x + gridDim.x * (blockIdx.y + gridDim.y * blockIdx.z);
    ssim_tile(X, Y, H, gw, Plevel, last_level, Xpool, Ypool,
              bc, blockIdx.y * TS, blockIdx.x * TS, lin, U, red);
}

__global__ void finalize_kernel(const float* __restrict__ P, float* __restrict__ out) {
    __shared__ float red[64][4];
    const int tid  = threadIdx.x;
    const int pair = tid >> 2;
    const int chnk = tid & 3;
    const int l = pair >> 4, b = pair & 15;
    float s = 0.f;
    #pragma unroll 4
    for (int j = 0; j < 64; ++j)
        s += P[((l * NBIN) + (chnk * 64) + j) * 16 + b];
    red[pair][chnk] = s;
    __syncthreads();
    if (tid < 16) {
        const int bb = tid;
        const float wraw[4] = {0.0448f, 0.2856f, 0.3001f, 0.2363f};
        float wsum = wraw[0] + wraw[1] + wraw[2] + wraw[3];
        float ms = 1.f;
        for (int ll = 0; ll < 4; ++ll) {
            int Hh = 512 >> ll;
            int Ho = Hh - HALO;
            float cnt = 3.f * (float)Ho * (float)Ho;
            float val = (red[ll * 16 + bb][0] + red[ll * 16 + bb][1] +
                         red[ll * 16 + bb][2] + red[ll * 16 + bb][3]) / cnt;
            val = fmaxf(val, 1e-8f);
            ms *= powf(val, wraw[ll] / wsum);
        }
        out[bb] = 1.f - ms;
    }
}

extern "C" void kernel_launch(void* const* d_in, const int* in_sizes, int n_in,
                              void* d_out, int out_size, void* d_ws, size_t ws_size,
                              hipStream_t stream)
{
    const float* X0 = (const float*)d_in[0];
    const float* Y0 = (const float*)d_in[1];
    float* out = (float*)d_out;
    float* ws  = (float*)d_ws;

    const size_t PSZ = (size_t)4 * NBIN * 16;
    float* P  = ws + BARW;
    float* X1 = P  + PSZ;
    float* Y1 = X1 + (size_t)16 * 3 * 256 * 256;
    float* X2 = Y1 + (size_t)16 * 3 * 256 * 256;
    float* Y2 = X2 + (size_t)16 * 3 * 128 * 128;
    float* X3 = Y2 + (size_t)16 * 3 * 128 * 128;
    float* Y3 = X3 + (size_t)16 * 3 * 64 * 64;

    GaussW gw;
    {
        float s = 0.f;
        for (int i = 0; i < 11; ++i) {
            float d = (float)(i - 5);
            gw.g[i] = expf(-d * d / (2.f * 1.5f * 1.5f));
            s += gw.g[i];
        }
        for (int i = 0; i < 11; ++i) gw.g[i] /= s;
    }

    // zero barrier state + P accumulators (ws may be poisoned between runs)
    hipMemsetAsync(ws, 0, (BARW + PSZ) * sizeof(float), stream);

    // grid sized to guaranteed co-residency (computed once; capture-safe queries)
    static int s_grid = 0;
    if (s_grid == 0) {
        int nb = 0;
        if (hipOccupancyMaxActiveBlocksPerMultiprocessor(&nb, ms_ssim_mega, 256, 0) != hipSuccess)
            nb = 0;
        if (nb > 6) nb = 6;
        int dev = 0;
        hipGetDevice(&dev);
        int ncu = 0;
        if (hipDeviceGetAttribute(&ncu, hipDeviceAttributeMultiprocessorCount, dev) != hipSuccess || ncu < 64)
            ncu = 256;
        s_grid = (nb * ncu) & ~(NG - 1);    // barrier needs grid % 64 == 0
        if (s_grid < NG) s_grid = -1;       // occupancy discovery failed -> fallback
    }

    if (s_grid > 0) {
        hipLaunchKernelGGL(ms_ssim_mega, dim3(s_grid), dim3(256), 0, stream,
                           X0, Y0, ws, out, gw);
    } else {
        hipLaunchKernelGGL(ssim_level_kernel, dim3(16, 16, 48), dim3(256), 0, stream,
                           X0, Y0, 512, gw, P + 0 * NBIN * 16, 0, X1, Y1);
        hipLaunchKernelGGL(ssim_level_kernel, dim3(8, 8, 48),   dim3(256), 0, stream,
                           X1, Y1, 256, gw, P + 1 * NBIN * 16, 0, X2, Y2);
        hipLaunchKernelGGL(ssim_level_kernel, dim3(4, 4, 48),   dim3(256), 0, stream,
                           X2, Y2, 128, gw, P + 2 * NBIN * 16, 0, X3, Y3);
        hipLaunchKernelGGL(ssim_level_kernel, dim3(2, 2, 48),   dim3(256), 0, stream,
                           X3, Y3, 64,  gw, P + 3 * NBIN * 16, 1, (float*)nullptr, (float*)nullptr);
        hipLaunchKernelGGL(finalize_kernel, dim3(1), dim3(256), 0, stream, P, out);
    }
}

// Round 4
// 246.493 us; speedup vs baseline: 1.5733x; 1.5733x over previous
//
#include <hip/hip_runtime.h>
#include <math.h>

#define HALO 10
#define TS 32
#define IN 42      // TS + HALO rows staged
#define NP 21      // float2 pairs staged per row (42 cols; window needs <=41)
#define XSTR 46    // LDS row stride (words) for Xs/Ys
#define HSTR 46    // LDS row stride (words) for Hs (transposed)
#define NBIN 256   // atomic spreading: one 64B line (16 floats) per bin per level
#define NG 64      // barrier groups (each counter/gen copy on its own 64B line)
#define BARW 2112  // uints reserved for barrier state (16 + 64*16 + 64*16 = 2064, padded)

typedef float f2 __attribute__((ext_vector_type(2)));

struct GaussW { float g[11]; };

// ---------------- relaxed grid barrier: NO fences, NO bulk cache maintenance ----
// All cross-block data goes through agent-scope (MALL-coherent) accesses, so the
// barrier only needs arrival counting + ordering by data dependency:
//   - entry __syncthreads() drains every wave's vmcnt (compiler emits
//     s_waitcnt vmcnt(0) before s_barrier), so all sc1 stores are at the
//     coherence point before tid0 signals arrival.
//   - RMW return values chain writer -> group -> root causally.
//   - explicit vmcnt(0) between counter-reset stores and next-level RMW kills
//     the same-wave store/RMW reorder race on the counters.
// bar layout (uints): [0] root | [16+g*16] group counters | [16+NG*16+g*16] gen copies
__device__ __forceinline__ void grid_barrier(unsigned* bar)
{
    __syncthreads();
    if (threadIdx.x == 0) {
        unsigned* root  = bar;
        unsigned* grp   = bar + 16 + (blockIdx.x & (NG - 1)) * 16;
        unsigned* mygen = bar + 16 + NG * 16 + (blockIdx.x & (NG - 1)) * 16;
        const unsigned gsz = gridDim.x / NG;

        unsigned gen = __hip_atomic_load(mygen, __ATOMIC_RELAXED, __HIP_MEMORY_SCOPE_AGENT);
        asm volatile("s_waitcnt vmcnt(0)" ::: "memory");   // my stores are at MALL
        unsigned a = __hip_atomic_fetch_add(grp, 1u, __ATOMIC_RELAXED, __HIP_MEMORY_SCOPE_AGENT);
        if (a == gsz - 1u) {                       // last of my group
            __hip_atomic_store(grp, 0u, __ATOMIC_RELAXED, __HIP_MEMORY_SCOPE_AGENT);
            asm volatile("s_waitcnt vmcnt(0)" ::: "memory");   // reset lands before root bump
            unsigned r = __hip_atomic_fetch_add(root, 1u, __ATOMIC_RELAXED, __HIP_MEMORY_SCOPE_AGENT);
            if (r == NG - 1u) {                    // last overall: release everyone
                __hip_atomic_store(root, 0u, __ATOMIC_RELAXED, __HIP_MEMORY_SCOPE_AGENT);
                asm volatile("s_waitcnt vmcnt(0)" ::: "memory");   // root reset lands first
                unsigned* gc = bar + 16 + NG * 16;
                #pragma unroll 4
                for (int i = 0; i < NG; ++i)
                    __hip_atomic_store(gc + i * 16, gen + 1u, __ATOMIC_RELAXED, __HIP_MEMORY_SCOPE_AGENT);
            }
        }
        unsigned spin = 0;
        while (__hip_atomic_load(mygen, __ATOMIC_RELAXED, __HIP_MEMORY_SCOPE_AGENT) == gen) {
            __builtin_amdgcn_s_sleep(4);
            if (++spin > (1u << 20)) break;        // watchdog: wrong > hung
        }
        asm volatile("" ::: "memory");             // compiler-only ordering
    }
    __syncthreads();
}

// ---------------- per-tile SSIM level body (math identical to the 201us kernel) ----
// agent_in != 0: inputs are pool buffers -> read via agent-scope (MALL) loads.
// Pool writes are always agent-scope stores. X0/Y0 keep the cached path.
__device__ __forceinline__ void ssim_tile(
    const float* __restrict__ X, const float* __restrict__ Y,
    int H, const GaussW& gw, float* __restrict__ Plevel, int last_level,
    float* __restrict__ Xpool, float* __restrict__ Ypool,
    int bc, int r0, int c0, int lin, int agent_in, float* U, float* red)
{
    const int W = H;
    const int Hout = H - HALO;
    float* Xs = U;                    // [IN][XSTR]
    float* Ys = U + IN * XSTR;        // [IN][XSTR]
    const int tid = threadIdx.x;
    const int b   = bc / 3;
    const size_t base = (size_t)bc * H * W;

    // Phase 1: coalesced staging
    for (int idx = tid; idx < IN * NP; idx += 256) {
        int rr = idx / NP, pp = idx - rr * NP;
        int gr = r0 + rr, gc = c0 + 2 * pp;
        float2 xv = make_float2(0.f, 0.f), yv = make_float2(0.f, 0.f);
        if (gr < H && gc < W) {
            const float* xp = X + base + (size_t)gr * W + gc;
            const float* yp = Y + base + (size_t)gr * W + gc;
            if (agent_in) {
                unsigned long long xb = __hip_atomic_load((const unsigned long long*)xp,
                                            __ATOMIC_RELAXED, __HIP_MEMORY_SCOPE_AGENT);
                unsigned long long yb = __hip_atomic_load((const unsigned long long*)yp,
                                            __ATOMIC_RELAXED, __HIP_MEMORY_SCOPE_AGENT);
                xv = __builtin_bit_cast(float2, xb);
                yv = __builtin_bit_cast(float2, yb);
            } else {
                xv = *(const float2*)xp;
                yv = *(const float2*)yp;
            }
        }
        *(float2*)&Xs[rr * XSTR + 2 * pp] = xv;
        *(float2*)&Ys[rr * XSTR + 2 * pp] = yv;
    }
    __syncthreads();

    // Phase 2a: windows -> registers (waves 0-2); 2x2 pool (wave 3, agent stores)
    float x[18], y[18];
    int rr = 0, ccb = 0;
    if (tid < 168) {
        rr  = tid >> 2;
        ccb = (tid & 3) * 8;
        #pragma unroll
        for (int u = 0; u < 9; ++u) {
            *(f2*)&x[2 * u] = *(const f2*)&Xs[rr * XSTR + ccb + 2 * u];
            *(f2*)&y[2 * u] = *(const f2*)&Ys[rr * XSTR + ccb + 2 * u];
        }
    } else if (tid >= 192 && !last_level) {
        const int t = tid - 192;
        const int Wp = W >> 1;
        #pragma unroll
        for (int q = 0; q < 4; ++q) {
            int cell = q * 64 + t;
            int pr = cell >> 4, pc = cell & 15;
            float2 xa = *(const float2*)&Xs[(2 * pr)     * XSTR + 2 * pc];
            float2 xb = *(const float2*)&Xs[(2 * pr + 1) * XSTR + 2 * pc];
            float2 ya = *(const float2*)&Ys[(2 * pr)     * XSTR + 2 * pc];
            float2 yb = *(const float2*)&Ys[(2 * pr + 1) * XSTR + 2 * pc];
            size_t o = (size_t)bc * (H >> 1) * Wp + (size_t)(r0 / 2 + pr) * Wp + (c0 / 2 + pc);
            __hip_atomic_store(&Xpool[o], 0.25f * (xa.x + xa.y + xb.x + xb.y),
                               __ATOMIC_RELAXED, __HIP_MEMORY_SCOPE_AGENT);
            __hip_atomic_store(&Ypool[o], 0.25f * (ya.x + ya.y + yb.x + yb.y),
                               __ATOMIC_RELAXED, __HIP_MEMORY_SCOPE_AGENT);
        }
    }
    __syncthreads();   // all Xs/Ys reads done -> Hs may overwrite

    // Phase 2b: horizontal 11-tap blur of {x, y, (x+y)^2, (x-y)^2}
    if (tid < 168) {
        #pragma unroll
        for (int p = 0; p < 4; ++p) {
            f2 ax = {0.f, 0.f}, ay = {0.f, 0.f};
            #pragma unroll
            for (int k = 0; k < 11; ++k) {
                f2 vx = { x[2 * p + k], x[2 * p + k + 1] };
                f2 vy = { y[2 * p + k], y[2 * p + k + 1] };
                ax += vx * gw.g[k];
                ay += vy * gw.g[k];
            }
            U[(0 * TS + ccb + 2 * p    ) * HSTR + rr] = ax.x;
            U[(0 * TS + ccb + 2 * p + 1) * HSTR + rr] = ax.y;
            U[(1 * TS + ccb + 2 * p    ) * HSTR + rr] = ay.x;
            U[(1 * TS + ccb + 2 * p + 1) * HSTR + rr] = ay.y;
        }
        #pragma unroll
        for (int i = 0; i < 9; ++i) {
            f2 xv = *(f2*)&x[2 * i];
            f2 yv = *(f2*)&y[2 * i];
            f2 a = xv + yv;
            f2 d = xv - yv;
            *(f2*)&x[2 * i] = a * a;
            *(f2*)&y[2 * i] = d * d;
        }
        #pragma unroll
        for (int p = 0; p < 4; ++p) {
            f2 as = {0.f, 0.f}, ad = {0.f, 0.f};
            #pragma unroll
            for (int k = 0; k < 11; ++k) {
                f2 vs = { x[2 * p + k], x[2 * p + k + 1] };
                f2 vd = { y[2 * p + k], y[2 * p + k + 1] };
                as += vs * gw.g[k];
                ad += vd * gw.g[k];
            }
            U[(2 * TS + ccb + 2 * p    ) * HSTR + rr] = as.x;
            U[(2 * TS + ccb + 2 * p + 1) * HSTR + rr] = as.y;
            U[(3 * TS + ccb + 2 * p    ) * HSTR + rr] = ad.x;
            U[(3 * TS + ccb + 2 * p + 1) * HSTR + rr] = ad.y;
        }
    }
    __syncthreads();

    // Phase 3: vertical 11-tap blur + SSIM
    const int tx = tid & 31;
    const int ty = tid >> 5;
    const int rb = ty * 4;

    f2 m1[2], m2[2], S[2], D[2];
    #define VPASS(Q, OUT)                                                          \
    {                                                                              \
        float win[14];                                                             \
        _Pragma("unroll")                                                          \
        for (int i = 0; i < 7; ++i)                                                \
            *(f2*)&win[2 * i] = *(const f2*)&U[(Q * TS + tx) * HSTR + rb + 2 * i]; \
        _Pragma("unroll")                                                          \
        for (int h = 0; h < 2; ++h) {                                              \
            f2 acc = {0.f, 0.f};                                                   \
            _Pragma("unroll")                                                      \
            for (int k = 0; k < 11; ++k) {                                         \
                f2 v = { win[2 * h + k], win[2 * h + k + 1] };                     \
                acc += v * gw.g[k];                                                \
            }                                                                      \
            OUT[h] = acc;                                                          \
        }                                                                          \
    }
    VPASS(0, m1) VPASS(1, m2) VPASS(2, S) VPASS(3, D)
    #undef VPASS

    const float C1 = 1e-4f, C2 = 9e-4f;
    float acc_s = 0.f;
    #pragma unroll
    for (int o = 0; o < 4; ++o) {
        float u1 = m1[o >> 1][o & 1], u2 = m2[o >> 1][o & 1];
        float Sv = S[o >> 1][o & 1],  Dv = D[o >> 1][o & 1];
        float u1s = u1 * u1, u2s = u2 * u2, u12 = u1 * u2;
        float ssum = 0.5f  * (Sv + Dv);
        float sxy  = 0.25f * (Sv - Dv);
        float vsum = ssum - u1s - u2s;
        float v12  = sxy - u12;
        float A2   = fmaxf(2.f * v12 + C2, 0.f);
        float B1   = u1s + u2s + C1;
        float B2   = vsum + C2;
        float inv  = __builtin_amdgcn_rcpf(B1 * B2);
        float val;
        if (!last_level) {
            val = A2 * B1 * inv;
        } else {
            float A1 = 2.f * u12 + C1;
            val = A1 * A2 * inv;
        }
        bool valid = (r0 + rb + o < Hout) && (c0 + tx < Hout);
        acc_s += valid ? val : 0.f;
    }

    // Phase 4: block reduction + one atomic
    #pragma unroll
    for (int off = 32; off; off >>= 1) acc_s += __shfl_down(acc_s, off);
    if ((tid & 63) == 0) red[tid >> 6] = acc_s;
    __syncthreads();
    if (tid == 0) {
        int bin = lin & (NBIN - 1);
        atomicAdd(&Plevel[bin * 16 + b], red[0] + red[1] + red[2] + red[3]);
    }
}

// ---------------- fused persistent kernel: all 4 levels + finalize ----------------
__global__ __launch_bounds__(256, 6) void ms_ssim_mega(
    const float* __restrict__ X0, const float* __restrict__ Y0,
    float* __restrict__ ws, float* __restrict__ out, GaussW gw)
{
    __shared__ float U[4 * TS * HSTR];
    __shared__ float red[4];

    unsigned* bar = (unsigned*)ws;
    const size_t PSZ = (size_t)4 * NBIN * 16;
    float* P  = ws + BARW;
    float* X1 = P  + PSZ;
    float* Y1 = X1 + (size_t)16 * 3 * 256 * 256;
    float* X2 = Y1 + (size_t)16 * 3 * 256 * 256;
    float* Y2 = X2 + (size_t)16 * 3 * 128 * 128;
    float* X3 = Y2 + (size_t)16 * 3 * 128 * 128;
    float* Y3 = X3 + (size_t)16 * 3 * 64 * 64;

    #pragma unroll 1
    for (int L = 0; L < 4; ++L) {
        const int H   = 512 >> L;
        const int lg2 = 2 * (4 - L);          // log2((H/32)^2): 8,6,4,2
        const int ntiles = 48 << lg2;
        const int last = (L == 3);
        float* Pl = P + L * NBIN * 16;
        const float *Xi, *Yi; float *Xo, *Yo;
        if      (L == 0) { Xi = X0; Yi = Y0; Xo = X1; Yo = Y1; }
        else if (L == 1) { Xi = X1; Yi = Y1; Xo = X2; Yo = Y2; }
        else if (L == 2) { Xi = X2; Yi = Y2; Xo = X3; Yo = Y3; }
        else             { Xi = X3; Yi = Y3; Xo = nullptr; Yo = nullptr; }

        for (int t = blockIdx.x; t < ntiles; t += gridDim.x) {
            const int bc  = t >> lg2;
            const int rem = t & ((1 << lg2) - 1);
            const int tyi = rem >> (4 - L);
            const int txi = rem & ((H >> 5) - 1);
            ssim_tile(Xi, Yi, H, gw, Pl, last, Xo, Yo,
                      bc, tyi * TS, txi * TS, t, (L > 0), U, red);
        }
        grid_barrier(bar);
    }

    // finalize in block 0 (agent loads: P lines are never plain-cached)
    if (blockIdx.x == 0) {
        float* fin = U;                    // [64][4]
        const int tid  = threadIdx.x;
        const int pair = tid >> 2;
        const int chnk = tid & 3;
        const int l = pair >> 4, b = pair & 15;
        float s = 0.f;
        #pragma unroll 4
        for (int j = 0; j < 64; ++j)
            s += __hip_atomic_load(&P[((l * NBIN) + (chnk * 64) + j) * 16 + b],
                                   __ATOMIC_RELAXED, __HIP_MEMORY_SCOPE_AGENT);
        fin[pair * 4 + chnk] = s;
        __syncthreads();
        if (tid < 16) {
            const int bb = tid;
            const float wraw[4] = {0.0448f, 0.2856f, 0.3001f, 0.2363f};
            float wsum = wraw[0] + wraw[1] + wraw[2] + wraw[3];
            float ms = 1.f;
            for (int ll = 0; ll < 4; ++ll) {
                int Hh = 512 >> ll;
                int Ho = Hh - HALO;
                float cnt = 3.f * (float)Ho * (float)Ho;
                float val = (fin[(ll * 16 + bb) * 4 + 0] + fin[(ll * 16 + bb) * 4 + 1] +
                             fin[(ll * 16 + bb) * 4 + 2] + fin[(ll * 16 + bb) * 4 + 3]) / cnt;
                val = fmaxf(val, 1e-8f);
                ms *= powf(val, wraw[ll] / wsum);
            }
            out[bb] = 1.f - ms;
        }
    }
}

// ---------------- fallback: proven per-level chain ----------------
__global__ __launch_bounds__(256, 6) void ssim_level_kernel(
    const float* __restrict__ X, const float* __restrict__ Y,
    int H, GaussW gw, float* __restrict__ Plevel, int last_level, int agent_in,
    float* __restrict__ Xpool, float* __restrict__ Ypool)
{
    __shared__ float U[4 * TS * HSTR];
    __shared__ float red[4];
    const int bc = blockIdx.z;
    const int lin = blockIdx.x + gridDim.x * (blockIdx.y + gridDim.y * blockIdx.z);
    ssim_tile(X, Y, H, gw, Plevel, last_level, Xpool, Ypool,
              bc, blockIdx.y * TS, blockIdx.x * TS, lin, agent_in, U, red);
}

__global__ void finalize_kernel(const float* __restrict__ P, float* __restrict__ out) {
    __shared__ float red[64][4];
    const int tid  = threadIdx.x;
    const int pair = tid >> 2;
    const int chnk = tid & 3;
    const int l = pair >> 4, b = pair & 15;
    float s = 0.f;
    #pragma unroll 4
    for (int j = 0; j < 64; ++j)
        s += __hip_atomic_load(&P[((l * NBIN) + (chnk * 64) + j) * 16 + b],
                               __ATOMIC_RELAXED, __HIP_MEMORY_SCOPE_AGENT);
    red[pair][chnk] = s;
    __syncthreads();
    if (tid < 16) {
        const int bb = tid;
        const float wraw[4] = {0.0448f, 0.2856f, 0.3001f, 0.2363f};
        float wsum = wraw[0] + wraw[1] + wraw[2] + wraw[3];
        float ms = 1.f;
        for (int ll = 0; ll < 4; ++ll) {
            int Hh = 512 >> ll;
            int Ho = Hh - HALO;
            float cnt = 3.f * (float)Ho * (float)Ho;
            float val = (red[ll * 16 + bb][0] + red[ll * 16 + bb][1] +
                         red[ll * 16 + bb][2] + red[ll * 16 + bb][3]) / cnt;
            val = fmaxf(val, 1e-8f);
            ms *= powf(val, wraw[ll] / wsum);
        }
        out[bb] = 1.f - ms;
    }
}

extern "C" void kernel_launch(void* const* d_in, const int* in_sizes, int n_in,
                              void* d_out, int out_size, void* d_ws, size_t ws_size,
                              hipStream_t stream)
{
    const float* X0 = (const float*)d_in[0];
    const float* Y0 = (const float*)d_in[1];
    float* out = (float*)d_out;
    float* ws  = (float*)d_ws;

    const size_t PSZ = (size_t)4 * NBIN * 16;
    float* P  = ws + BARW;
    float* X1 = P  + PSZ;
    float* Y1 = X1 + (size_t)16 * 3 * 256 * 256;
    float* X2 = Y1 + (size_t)16 * 3 * 256 * 256;
    float* Y2 = X2 + (size_t)16 * 3 * 128 * 128;
    float* X3 = Y2 + (size_t)16 * 3 * 128 * 128;
    float* Y3 = X3 + (size_t)16 * 3 * 64 * 64;

    GaussW gw;
    {
        float s = 0.f;
        for (int i = 0; i < 11; ++i) {
            float d = (float)(i - 5);
            gw.g[i] = expf(-d * d / (2.f * 1.5f * 1.5f));
            s += gw.g[i];
        }
        for (int i = 0; i < 11; ++i) gw.g[i] /= s;
    }

    // zero barrier state + P accumulators (ws may be poisoned between runs)
    hipMemsetAsync(ws, 0, (BARW + PSZ) * sizeof(float), stream);

    // grid sized to guaranteed co-residency (computed once; capture-safe queries)
    static int s_grid = 0;
    if (s_grid == 0) {
        int nb = 0;
        if (hipOccupancyMaxActiveBlocksPerMultiprocessor(&nb, ms_ssim_mega, 256, 0) != hipSuccess)
            nb = 0;
        if (nb > 6) nb = 6;
        int dev = 0;
        hipGetDevice(&dev);
        int ncu = 0;
        if (hipDeviceGetAttribute(&ncu, hipDeviceAttributeMultiprocessorCount, dev) != hipSuccess || ncu < 64)
            ncu = 256;
        s_grid = (nb * ncu) & ~(NG - 1);    // barrier needs grid % 64 == 0
        if (s_grid < NG) s_grid = -1;       // occupancy discovery failed -> fallback
    }

    if (s_grid > 0) {
        hipLaunchKernelGGL(ms_ssim_mega, dim3(s_grid), dim3(256), 0, stream,
                           X0, Y0, ws, out, gw);
    } else {
        hipLaunchKernelGGL(ssim_level_kernel, dim3(16, 16, 48), dim3(256), 0, stream,
                           X0, Y0, 512, gw, P + 0 * NBIN * 16, 0, 0, X1, Y1);
        hipLaunchKernelGGL(ssim_level_kernel, dim3(8, 8, 48),   dim3(256), 0, stream,
                           X1, Y1, 256, gw, P + 1 * NBIN * 16, 0, 1, X2, Y2);
        hipLaunchKernelGGL(ssim_level_kernel, dim3(4, 4, 48),   dim3(256), 0, stream,
                           X2, Y2, 128, gw, P + 2 * NBIN * 16, 0, 1, X3, Y3);
        hipLaunchKernelGGL(ssim_level_kernel, dim3(2, 2, 48),   dim3(256), 0, stream,
                           X3, Y3, 64,  gw, P + 3 * NBIN * 16, 1, 1, (float*)nullptr, (float*)nullptr);
        hipLaunchKernelGGL(finalize_kernel, dim3(1), dim3(256), 0, stream, P, out);
    }
}